// Round 7
// baseline (160.810 us; speedup 1.0000x reference)
//
#include <hip/hip_runtime.h>

// BaconAdditionReasoner: y[b,k] = norm_k( 1 - prod_{i+j==k} (1 - clamp(min(p1p_i, p2p_j))) )
// p1p = p1 @ minmax_norm(W1), p2p = p2 @ minmax_norm(W2).
//
// Kept: R2 algebra (max(1-A,1-B) form, clamps dropped), R4 LDS weights + fused
// prep, R9 2-rows/thread weight amortization + pk_fma + nontemporal stores.
//
// R11: DMA-pipelined streaming. Rounds 0-10 varied fetch pattern, occupancy
// (57->15%), barriers, persistence, instruction count (-30%), block shape --
// dur pinned at 47-52us. Common invariant found by Little's law: avg
// bytes-in-flight ~2-3KB/CU (need ~9KB for 6.3TB/s at ~900cy latency).
// Register prefetch can't fix it: VGPR lifetime forces either load-sinking
// (R0-R6) or a ~15% duty cycle (R9/R10 compute with nothing in flight).
// global_load_lds decouples issue from VGPRs: 3-slot LDS ring, panels issued
// 3 ahead (30KB/wave outstanding), counted vmcnt(20) waits (never 0 until
// tail), 1024 persistent 1-wave blocks x 8 panels x 128 rows. Worst case
// (compiler adds vmcnt(0) before ds_reads) still leaves issue 3 panels early
// -> memory stream stays deep. Budget: VALU ~4.4us, LDS ~11us, HBM 162MB
// ~26us -> memory-bound target ~28-34us.
// Tripwire: FETCH ~41MB / WRITE 77824KB (excess = spills).

typedef float v2f __attribute__((ext_vector_type(2)));
typedef float v4f __attribute__((ext_vector_type(4)));
typedef __attribute__((address_space(3))) unsigned int lds_u32;
typedef const __attribute__((address_space(1))) unsigned int g_u32;

#define NBLOCKS 1024
#define TPB 64
#define PANELS 8          // 1024 blocks * 8 panels * 128 rows = 1048576 = B
#define PROWS 128         // rows per panel; 128*40B = 5120B = 5 * (64 lanes * 16B)
#define SLOTS 3           // LDS ring depth

__global__ __launch_bounds__(TPB) void bacon_main(
    const float* __restrict__ p1, const float* __restrict__ p2,
    const float* __restrict__ W1, const float* __restrict__ W2,
    float* __restrict__ out)
{
    // ring: [slot][p1 panel 1280f | p2 panel 1280f] = 10240B/slot, 3 slots
    __shared__ __align__(16) float s_in[SLOTS][2560];
    __shared__ __align__(16) float s_out[TPB * 19];   // 4864B store stage
    __shared__ __align__(16) float s_w[240];          // wn: [2][10][12] stride-12
    // total LDS = 30720 + 4864 + 960 = 36544B -> 4 blocks/CU (LDS-capped)

    const int t = threadIdx.x;                        // 0..63
    const int blk = blockIdx.x;
    const size_t blk_row0 = (size_t)blk * (PANELS * PROWS);

    // ---- DMA stage: 5 x 16B/lane per array -> linear LDS (wave-uniform dest) ----
    auto stage = [&](int p, int s) {
        g_u32* gp1 = (g_u32*)(p1 + (blk_row0 + (size_t)p * PROWS) * 10);
        g_u32* gp2 = (g_u32*)(p2 + (blk_row0 + (size_t)p * PROWS) * 10);
        lds_u32* l1 = (lds_u32*)&s_in[s][0];
        lds_u32* l2 = (lds_u32*)&s_in[s][1280];
        #pragma unroll
        for (int i = 0; i < 5; ++i) {
            __builtin_amdgcn_global_load_lds(gp1 + i * 256 + t * 4, l1 + i * 256, 16, 0, 0);
            __builtin_amdgcn_global_load_lds(gp2 + i * 256 + t * 4, l2 + i * 256, 16, 0, 0);
        }
    };

    // ---- prologue: fill the ring 3 deep (30 loads, 30KB in flight) ----
    stage(0, 0);
    stage(1, 1);
    stage(2, 2);

    // ---- fused prep: lanes 0..19 minmax-normalize one W row into LDS ----
    if (t < 20) {
        const float* row = ((t < 10) ? W1 : W2) + (t % 10) * 10;
        float r[10];
        #pragma unroll
        for (int i = 0; i < 10; ++i) r[i] = row[i];
        float lo = r[0], hi = r[0];
        #pragma unroll
        for (int i = 1; i < 10; ++i) {
            lo = fminf(lo, r[i]);
            hi = fmaxf(hi, r[i]);
        }
        float inv = 1.0f / (hi - lo + 1e-8f);
        float* o = s_w + ((t < 10) ? 0 : 120) + (t % 10) * 12;
        #pragma unroll
        for (int i = 0; i < 10; ++i) o[i] = (r[i] - lo) * inv;
        o[10] = 0.0f; o[11] = 0.0f;
    }
    __syncthreads();   // 1-wave: orders s_w writes vs reads, near-free

    #pragma unroll
    for (int p = 0; p < PANELS; ++p) {
        const int s = p % SLOTS;

        // ---- counted wait: panel p's 10 DMAs done, keep 2 panels in flight ----
        // issued so far = 30 + 10*min(p,PANELS-SLOTS); need completed >= 10*(p+1)
        if (p <= PANELS - SLOTS) {          // p<=5: 2 younger panels stay in flight
            asm volatile("s_waitcnt vmcnt(20)" ::: "memory");
        } else if (p == PANELS - 2) {       // p=6: 1 younger panel in flight
            asm volatile("s_waitcnt vmcnt(10)" ::: "memory");
        } else {                            // p=7: drain
            asm volatile("s_waitcnt vmcnt(0)" ::: "memory");
        }
        __builtin_amdgcn_sched_barrier(0);

        // ---- read own 2 rows (t and t+64) from the slot: 5 x b64 per array ----
        float a[2][10], b[2][10];
        #pragma unroll
        for (int rr = 0; rr < 2; ++rr) {
            const int row = rr * 64 + t;
            const v2f* r1 = (const v2f*)&s_in[s][row * 10];
            const v2f* r2 = (const v2f*)&s_in[s][1280 + row * 10];
            #pragma unroll
            for (int e = 0; e < 5; ++e) {
                v2f x = r1[e], y = r2[e];
                a[rr][2 * e] = x.x; a[rr][2 * e + 1] = x.y;
                b[rr][2 * e] = y.x; b[rr][2 * e + 1] = y.y;
            }
        }
        // rows now headed to VGPRs; ensure LDS reads retired before slot reuse
        asm volatile("s_waitcnt lgkmcnt(0)" ::: "memory");
        __builtin_amdgcn_sched_barrier(0);

        // ---- re-issue this slot for panel p+3 (overlaps with compute below) ----
        if (p + SLOTS < PANELS) stage(p + SLOTS, s);

        // ---- shared k-loop: weights read once per k for both rows; pk_fma ----
        v2f A2[2][5], B2[2][5];
        #pragma unroll
        for (int rr = 0; rr < 2; ++rr)
            #pragma unroll
            for (int m = 0; m < 5; ++m) { A2[rr][m] = (v2f){1.0f, 1.0f}; B2[rr][m] = (v2f){1.0f, 1.0f}; }

        #pragma unroll
        for (int k = 0; k < 10; ++k) {
            const float4* w1q = (const float4*)(s_w + k * 12);          // 48B-aligned
            const float4* w2q = (const float4*)(s_w + 120 + k * 12);
            float4 u0 = w1q[0], u1 = w1q[1];
            float2 u2 = *(const float2*)(s_w + k * 12 + 8);
            float4 v0 = w2q[0], v1 = w2q[1];
            float2 v2 = *(const float2*)(s_w + 120 + k * 12 + 8);
            v2f uw[5] = { {u0.x, u0.y}, {u0.z, u0.w}, {u1.x, u1.y}, {u1.z, u1.w}, {u2.x, u2.y} };
            v2f vw[5] = { {v0.x, v0.y}, {v0.z, v0.w}, {v1.x, v1.y}, {v1.z, v1.w}, {v2.x, v2.y} };
            #pragma unroll
            for (int rr = 0; rr < 2; ++rr) {
                const v2f na = (v2f){-a[rr][k], -a[rr][k]};
                const v2f nb = (v2f){-b[rr][k], -b[rr][k]};
                #pragma unroll
                for (int m = 0; m < 5; ++m) {
                    A2[rr][m] = __builtin_elementwise_fma(na, uw[m], A2[rr][m]);  // v_pk_fma_f32
                    B2[rr][m] = __builtin_elementwise_fma(nb, vw[m], B2[rr][m]);
                }
            }
        }

        // ---- per-row epilogue: 100-pair product, normalize, staged store ----
        #pragma unroll
        for (int rr = 0; rr < 2; ++rr) {
            float A[10], Bv[10];
            #pragma unroll
            for (int m = 0; m < 5; ++m) {
                A[2 * m] = A2[rr][m].x;  A[2 * m + 1] = A2[rr][m].y;
                Bv[2 * m] = B2[rr][m].x; Bv[2 * m + 1] = B2[rr][m].y;
            }

            float prod[19];
            #pragma unroll
            for (int k = 0; k < 19; ++k) prod[k] = 1.0f;
            #pragma unroll
            for (int i = 0; i < 10; ++i) {
                #pragma unroll
                for (int j = 0; j < 10; ++j) {
                    prod[i + j] *= fmaxf(A[i], Bv[j]);
                }
            }

            float y[19];
            float tot = 0.0f;
            #pragma unroll
            for (int k = 0; k < 19; ++k) { y[k] = 1.0f - prod[k]; tot += y[k]; }
            float invn = __builtin_amdgcn_rcpf(tot + 1e-9f);

            // single buffer safe in-wave: LDS ops execute in program order
            #pragma unroll
            for (int k = 0; k < 19; ++k) s_out[t * 19 + k] = y[k] * invn;

            {
                const v4f* so = (const v4f*)s_out;                       // 304 vec4
                v4f* go = (v4f*)(out + (blk_row0 + (size_t)p * PROWS + rr * 64) * 19);
                #pragma unroll
                for (int it = 0; it < 5; ++it) {
                    int idx = t + it * TPB;
                    if (idx < 304)
                        __builtin_nontemporal_store(so[idx], go + idx);
                }
            }
        }
    }
}

extern "C" void kernel_launch(void* const* d_in, const int* in_sizes, int n_in,
                              void* d_out, int out_size, void* d_ws, size_t ws_size,
                              hipStream_t stream) {
    const float* p1 = (const float*)d_in[0];
    const float* p2 = (const float*)d_in[1];
    const float* W1 = (const float*)d_in[2];
    const float* W2 = (const float*)d_in[3];
    // d_in[4] = mask: bins are i+j, computed directly — mask unused.
    bacon_main<<<NBLOCKS, TPB, 0, stream>>>(p1, p2, W1, W2, (float*)d_out);
}

// Round 9
// 156.504 us; speedup vs baseline: 1.0275x; 1.0275x over previous
//
#include <hip/hip_runtime.h>

// BaconAdditionReasoner: y[b,k] = norm_k( 1 - prod_{i+j==k} (1 - clamp(min(p1p_i, p2p_j))) )
// p1p = p1 @ minmax_norm(W1), p2p = p2 @ minmax_norm(W2).
//
// Kept: R2 algebra (max(1-A,1-B), clamps dropped), R4 LDS weights + fused prep,
// R9 pk_fma matmul + nontemporal staged stores.
//
// R12: enforced register pipeline at real occupancy. R11's DMA ring failed for
// two identified reasons: vmcnt counts STORES (the counted waits drained the
// store stream every panel) and 1-wave persistent blocks left only 4 request
// generators per CU (occupancy 10.5%, 1.9 TB/s). R6's register version failed
// because nothing stopped the compiler sinking the prefetch loads into their
// uses. This round: 1024 blocks x 256 threads, 4 panels x 256 rows each,
// double-buffered FLOAT2 register prefetch with sched_barrier(0) pinning the
// issue point at the TOP of each panel (before compute). No hand vmcnt: the
// compiler emits a counted wait before the unpack of the current buffer, and
// in-order vmcnt retirement means later-issued stores don't gate it. ~12
// waves/CU x 5KB in flight = ~60KB/CU sustained vs ~9KB needed for full BW.
// Evidence this can work: R7's (accidental) continuous scratch traffic
// sustained 3.27 TB/s in this same kernel shape.
// Tripwire: FETCH ~41MB / WRITE 77824KB (excess = spills).
//
// (R13 = R12 resubmitted verbatim: round 8 bench was an infra failure —
// "MI355X container failed twice" — the kernel never ran.)

typedef float v2f __attribute__((ext_vector_type(2)));
typedef float v4f __attribute__((ext_vector_type(4)));

#define NBLOCKS 1024
#define TPB 256
#define PANELS 4          // 1024 blocks * 4 panels * 256 rows = 1048576 = B

__global__ __launch_bounds__(TPB) void bacon_main(
    const float* __restrict__ p1, const float* __restrict__ p2,
    const float* __restrict__ W1, const float* __restrict__ W2,
    float* __restrict__ out)
{
    __shared__ __align__(16) float s_out[2][TPB * 19];  // parity double-buffer
    __shared__ __align__(16) float s_w[240];            // wn: [2][10][12] stride-12
    // LDS = 38912 + 960 = 39872 B -> 4 blocks/CU possible; VGPR ~150 -> ~3.

    const int t = threadIdx.x;
    const int blk = blockIdx.x;
    const size_t blk_row0 = (size_t)blk * (PANELS * TPB);

    // ---- register double-buffer for the input rows (1 row/thread/panel) ----
    float2 va[2][5], vb[2][5];

    // prologue: issue panel 0 loads
    {
        const float2* g1 = (const float2*)(p1 + (blk_row0 + t) * 10);
        const float2* g2 = (const float2*)(p2 + (blk_row0 + t) * 10);
        #pragma unroll
        for (int e = 0; e < 5; ++e) { va[0][e] = g1[e]; vb[0][e] = g2[e]; }
    }
    __builtin_amdgcn_sched_barrier(0);   // pin the issue point

    // ---- fused prep: threads 0..19 minmax-normalize one W row into LDS ----
    if (t < 20) {
        const float* row = ((t < 10) ? W1 : W2) + (t % 10) * 10;
        float r[10];
        #pragma unroll
        for (int i = 0; i < 10; ++i) r[i] = row[i];
        float lo = r[0], hi = r[0];
        #pragma unroll
        for (int i = 1; i < 10; ++i) {
            lo = fminf(lo, r[i]);
            hi = fmaxf(hi, r[i]);
        }
        float inv = 1.0f / (hi - lo + 1e-8f);
        float* o = s_w + ((t < 10) ? 0 : 120) + (t % 10) * 12;
        #pragma unroll
        for (int i = 0; i < 10; ++i) o[i] = (r[i] - lo) * inv;
        o[10] = 0.0f; o[11] = 0.0f;
    }
    __syncthreads();

    #pragma unroll
    for (int p = 0; p < PANELS; ++p) {
        const int cur = p & 1;

        // ---- 1. issue next panel's loads FIRST; pin with sched_barrier ----
        if (p + 1 < PANELS) {
            const int nxt = cur ^ 1;
            const float2* g1 = (const float2*)(p1 + (blk_row0 + (size_t)(p + 1) * TPB + t) * 10);
            const float2* g2 = (const float2*)(p2 + (blk_row0 + (size_t)(p + 1) * TPB + t) * 10);
            #pragma unroll
            for (int e = 0; e < 5; ++e) { va[nxt][e] = g1[e]; vb[nxt][e] = g2[e]; }
            __builtin_amdgcn_sched_barrier(0);   // do not sink these below
        }

        // ---- 2. unpack current buffer (compiler emits counted vmcnt here) ----
        float a[10], b[10];
        #pragma unroll
        for (int e = 0; e < 5; ++e) {
            a[2 * e] = va[cur][e].x; a[2 * e + 1] = va[cur][e].y;
            b[2 * e] = vb[cur][e].x; b[2 * e + 1] = vb[cur][e].y;
        }

        // ---- 3. A_i = 1 - a@W1n, B_j = 1 - b@W2n; weights via LDS broadcast ----
        v2f A2[5], B2[5];
        #pragma unroll
        for (int m = 0; m < 5; ++m) { A2[m] = (v2f){1.0f, 1.0f}; B2[m] = (v2f){1.0f, 1.0f}; }
        #pragma unroll
        for (int k = 0; k < 10; ++k) {
            const float4* w1q = (const float4*)(s_w + k * 12);          // 48B-aligned
            const float4* w2q = (const float4*)(s_w + 120 + k * 12);
            float4 u0 = w1q[0], u1 = w1q[1];
            float2 u2 = *(const float2*)(s_w + k * 12 + 8);
            float4 v0 = w2q[0], v1 = w2q[1];
            float2 v2 = *(const float2*)(s_w + 120 + k * 12 + 8);
            v2f uw[5] = { {u0.x, u0.y}, {u0.z, u0.w}, {u1.x, u1.y}, {u1.z, u1.w}, {u2.x, u2.y} };
            v2f vw[5] = { {v0.x, v0.y}, {v0.z, v0.w}, {v1.x, v1.y}, {v1.z, v1.w}, {v2.x, v2.y} };
            const v2f na = (v2f){-a[k], -a[k]};
            const v2f nb = (v2f){-b[k], -b[k]};
            #pragma unroll
            for (int m = 0; m < 5; ++m) {
                A2[m] = __builtin_elementwise_fma(na, uw[m], A2[m]);  // v_pk_fma_f32
                B2[m] = __builtin_elementwise_fma(nb, vw[m], B2[m]);
            }
        }

        float A[10], Bv[10];
        #pragma unroll
        for (int m = 0; m < 5; ++m) {
            A[2 * m] = A2[m].x;  A[2 * m + 1] = A2[m].y;
            Bv[2 * m] = B2[m].x; Bv[2 * m + 1] = B2[m].y;
        }

        // ---- 4. per sum-bin product of max(A_i, B_j) ----
        float prod[19];
        #pragma unroll
        for (int k = 0; k < 19; ++k) prod[k] = 1.0f;
        #pragma unroll
        for (int i = 0; i < 10; ++i) {
            #pragma unroll
            for (int j = 0; j < 10; ++j) {
                prod[i + j] *= fmaxf(A[i], Bv[j]);
            }
        }

        float y[19];
        float tot = 0.0f;
        #pragma unroll
        for (int k = 0; k < 19; ++k) { y[k] = 1.0f - prod[k]; tot += y[k]; }
        float invn = __builtin_amdgcn_rcpf(tot + 1e-9f);

        // ---- 5. stage s_out[parity], one barrier, coalesced nontemporal store ----
        // parity safety: p's post-barrier reads precede p+1's barrier; p+2's
        // writes to the same buffer come after it (R6 scheme).
        #pragma unroll
        for (int k = 0; k < 19; ++k) s_out[cur][t * 19 + k] = y[k] * invn;
        __syncthreads();

        {
            const v4f* so = (const v4f*)s_out[cur];                     // 1216 vec4
            v4f* go = (v4f*)out + (size_t)(blk * PANELS + p) * 1216;
            #pragma unroll
            for (int it = 0; it < 5; ++it) {
                int idx = t + it * TPB;
                if (idx < 1216)                    // 1216 = 19*64: wave-uniform
                    __builtin_nontemporal_store(so[idx], go + idx);
            }
        }
    }
}

extern "C" void kernel_launch(void* const* d_in, const int* in_sizes, int n_in,
                              void* d_out, int out_size, void* d_ws, size_t ws_size,
                              hipStream_t stream) {
    const float* p1 = (const float*)d_in[0];
    const float* p2 = (const float*)d_in[1];
    const float* W1 = (const float*)d_in[2];
    const float* W2 = (const float*)d_in[3];
    // d_in[4] = mask: bins are i+j, computed directly — mask unused.
    bacon_main<<<NBLOCKS, TPB, 0, stream>>>(p1, p2, W1, W2, (float*)d_out);
}